// Round 10
// baseline (143.051 us; speedup 1.0000x reference)
//
#include <hip/hip_runtime.h>

#define BB 4
#define TQ 512
#define TK 512
#define DQ 512
#define UU 256
#define CSC 2.8853900817779268f   // 2*log2(e): Eq=2^(CSC*q), Ek=2^(CSC*k), e^{2y}=Eq*Ek
#define L2E 1.4426950408889634f
#define RQ 2

typedef unsigned short u16;
typedef unsigned int u32;
typedef short bf16x8 __attribute__((ext_vector_type(8)));
typedef float f32x4 __attribute__((ext_vector_type(4)));

__device__ __forceinline__ float fexp2(float x) { return __builtin_amdgcn_exp2f(x); }
__device__ __forceinline__ float frcp(float x)  { return __builtin_amdgcn_rcpf(x); }
// pack high 16 bits of two fp32 words: low16 = a.hi16, high16 = b.hi16
__device__ __forceinline__ u32 pkhi(u32 a, u32 b) { return (b & 0xffff0000u) | (a >> 16); }

// proj v2: C = A@W (CSC applied at epilogue), split-bf16 MFMA (truncation split, 3 terms).
// Tile 32m x 64n, K chunks of 32. Grid (64, 4, 2) = 512 blocks (2/CU), block 256 = 4 waves.
// Wave w owns n-frag cols [w*16, w*16+16). A staged as bf16 hi/lo planes (split once by
// loaders, b128 frag reads); W staged fp32 (coalesced), split in-reg per wave (no dup).
// z=0: Eq[m][u] = 2^(CSC*acc) row-major.  z=1: Ek interleaved [b][u/4][j][4] via bounce.
__global__ __launch_bounds__(256) void proj2(
    const float* __restrict__ Aq, const float* __restrict__ Av,
    const float* __restrict__ W1, const float* __restrict__ W2,
    float* __restrict__ Eq, float* __restrict__ Ek)
{
    __shared__ __align__(16) char raw[14336];
    u16*   As_h = (u16*)raw;                 // [32][40] u16, 80B rows (16B-aligned)
    u16*   As_l = (u16*)(raw + 2560);        // [32][40] u16
    float* Ws   = (float*)(raw + 5120);      // [32][72] f32, 288B rows
    float* fin  = (float*)raw;               // [32][68] f32, aliases after barrier

    const int z = blockIdx.z;
    const float* A = z ? Av : Aq;
    const float* W = z ? W2 : W1;

    const int t = threadIdx.x;
    const int m0 = blockIdx.x * 32, n0 = blockIdx.y * 64;
    const int wave = t >> 6, ln = t & 15, qd = (t & 63) >> 4;
    // staging maps
    const int arow = t >> 3, ak4 = (t & 7) * 4;    // A: 4 fp32 per thread
    const int wk = t >> 4, wn4 = (t & 15) * 4;     // W: 2x4 fp32 per thread

    f32x4 acc[2] = {};

    for (int k0 = 0; k0 < DQ; k0 += 32) {
        const float4 a4  = *(const float4*)&A[(size_t)(m0 + arow) * DQ + k0 + ak4];
        const float4 w40 = *(const float4*)&W[(size_t)(k0 + wk) * UU + n0 + wn4];
        const float4 w41 = *(const float4*)&W[(size_t)(k0 + 16 + wk) * UU + n0 + wn4];
        __syncthreads();   // previous chunk's LDS reads done
        {   // A split -> bf16 planes (once per value)
            const float f[4] = {a4.x, a4.y, a4.z, a4.w};
            u32 x[4], lx[4];
            #pragma unroll
            for (int e = 0; e < 4; e++) {
                x[e]  = __float_as_uint(f[e]);
                lx[e] = __float_as_uint(f[e] - __uint_as_float(x[e] & 0xffff0000u));
            }
            uint2 hw, lw;
            hw.x = pkhi(x[0], x[1]);  hw.y = pkhi(x[2], x[3]);
            lw.x = pkhi(lx[0], lx[1]); lw.y = pkhi(lx[2], lx[3]);
            *(uint2*)&As_h[arow * 40 + ak4] = hw;
            *(uint2*)&As_l[arow * 40 + ak4] = lw;
        }
        *(float4*)&Ws[wk * 72 + wn4] = w40;
        *(float4*)&Ws[(wk + 16) * 72 + wn4] = w41;
        __syncthreads();

        bf16x8 ah[2], al[2], bh, bl;
        #pragma unroll
        for (int i = 0; i < 2; i++) {
            const int ar = (i * 16 + ln) * 40 + qd * 8;
            ah[i] = *(const bf16x8*)&As_h[ar];
            al[i] = *(const bf16x8*)&As_l[ar];
        }
        {   // W frag: col = wave*16+ln, 8 consecutive k; split in-reg
            const int cl = wave * 16 + ln;
            float wf[8];
            #pragma unroll
            for (int e = 0; e < 8; e++) wf[e] = Ws[(qd * 8 + e) * 72 + cl];
            u32 y[8], ly[8];
            #pragma unroll
            for (int e = 0; e < 8; e++) {
                y[e]  = __float_as_uint(wf[e]);
                ly[e] = __float_as_uint(wf[e] - __uint_as_float(y[e] & 0xffff0000u));
            }
            union { uint4 u; bf16x8 v; } h, l;
            h.u.x = pkhi(y[0], y[1]);  h.u.y = pkhi(y[2], y[3]);
            h.u.z = pkhi(y[4], y[5]);  h.u.w = pkhi(y[6], y[7]);
            l.u.x = pkhi(ly[0], ly[1]); l.u.y = pkhi(ly[2], ly[3]);
            l.u.z = pkhi(ly[4], ly[5]); l.u.w = pkhi(ly[6], ly[7]);
            bh = h.v; bl = l.v;
        }
        #pragma unroll
        for (int i = 0; i < 2; i++) {
            acc[i] = __builtin_amdgcn_mfma_f32_16x16x32_bf16(ah[i], bh, acc[i], 0, 0, 0);
            acc[i] = __builtin_amdgcn_mfma_f32_16x16x32_bf16(ah[i], bl, acc[i], 0, 0, 0);
            acc[i] = __builtin_amdgcn_mfma_f32_16x16x32_bf16(al[i], bh, acc[i], 0, 0, 0);
        }
    }

    const int ncol = n0 + wave * 16 + ln;
    if (z == 0) {
        #pragma unroll
        for (int i = 0; i < 2; i++) {
            #pragma unroll
            for (int r = 0; r < 4; r++) {
                const int m = m0 + i * 16 + qd * 4 + r;
                Eq[(size_t)m * UU + ncol] = fexp2(CSC * acc[i][r]);
            }
        }
    } else {
        __syncthreads();   // staging reads done before aliasing with fin
        #pragma unroll
        for (int i = 0; i < 2; i++) {
            #pragma unroll
            for (int r = 0; r < 4; r++) {
                const int ml = i * 16 + qd * 4 + r;           // j-local 0..31
                const int nl = wave * 16 + ln;                // u-local 0..63
                fin[ml * 68 + nl] = fexp2(CSC * acc[i][r]);
            }
        }
        __syncthreads();
        const int b = m0 >> 9, j0 = m0 & 511;
        #pragma unroll
        for (int p = 0; p < 2; p++) {
            const int idx = p * 256 + t;
            const int jl = idx & 31, u4 = idx >> 5;           // u4 0..15
            const float4 v = *(const float4*)&fin[jl * 68 + u4 * 4];
            ((float4*)Ek)[(size_t)(b * (UU / 4) + (n0 >> 2) + u4) * TK + j0 + jl] = v;
        }
    }
}

// attn+softmax: e^{2y} = Eq*Ek; rcp paired over adjacent u (exact algebra):
// s0/d0 + s1/d1 = (s0*d1 + s1*d0) / (d0*d1); P <= 2^64 (Eq,Ek <= ~2^16), no overflow.
// shifted_score = -2 * sum; softmax shift-invariant.
__global__ __launch_bounds__(512) void attn_softmax(
    const float* __restrict__ Eq,    // [BB, TQ, UU]
    const float* __restrict__ Ek,    // [BB, UU/4, TK] of float4 (interleaved u)
    const float* __restrict__ scale, // [UU]
    float* __restrict__ out)         // [BB, TQ, TK]
{
    __shared__ float redbuf[RQ][8];
    const int t  = threadIdx.x;
    const int b  = blockIdx.x >> 8;            // 256 blocks per b
    const int q0 = (blockIdx.x & 255) * RQ;
    const float*  qrow = Eq + (size_t)(b * TQ + q0) * UU;   // wave-uniform
    const float4* kb4  = (const float4*)Ek + (size_t)b * (UU / 4) * TK + t;

    float acc[RQ] = {};
    float4 kbuf[4];
    #pragma unroll
    for (int i = 0; i < 4; i++) kbuf[i] = kb4[(size_t)i * TK];

    #pragma unroll 2
    for (int g = 0; g < UU / 4; g++) {
        const float4 kv = kbuf[g & 3];
        if (g + 4 < UU / 4) kbuf[g & 3] = kb4[(size_t)(g + 4) * TK];  // 4-deep prefetch
        const float4 sc4 = *(const float4*)&scale[4 * g];             // wave-uniform
        const float* sf = (const float*)&sc4;
        const float* kf = (const float*)&kv;
        #pragma unroll
        for (int r = 0; r < RQ; r++) {
            const float4 q4 = *(const float4*)&qrow[(size_t)r * UU + 4 * g];
            const float* qf = (const float*)&q4;
            #pragma unroll
            for (int p = 0; p < 4; p += 2) {
                const float d0 = fmaf(qf[p],     kf[p],     1.0f);
                const float d1 = fmaf(qf[p + 1], kf[p + 1], 1.0f);
                const float num = fmaf(sf[p], d1, sf[p + 1] * d0);
                acc[r] = fmaf(num, frcp(d0 * d1), acc[r]);
            }
        }
    }
    #pragma unroll
    for (int r = 0; r < RQ; r++) acc[r] *= -2.0f;

    const int wave = t >> 6, lane = t & 63;
    float m[RQ], p[RQ];

    // row max over 512 threads
    #pragma unroll
    for (int r = 0; r < RQ; r++) {
        float v = acc[r];
        #pragma unroll
        for (int o = 32; o > 0; o >>= 1) v = fmaxf(v, __shfl_xor(v, o));
        if (lane == 0) redbuf[r][wave] = v;
    }
    __syncthreads();
    #pragma unroll
    for (int r = 0; r < RQ; r++) {
        float v = redbuf[r][0];
        #pragma unroll
        for (int w = 1; w < 8; w++) v = fmaxf(v, redbuf[r][w]);
        m[r] = v;
    }
    __syncthreads();

    // exp and row sum
    #pragma unroll
    for (int r = 0; r < RQ; r++) {
        p[r] = fexp2(L2E * (acc[r] - m[r]));
        float v = p[r];
        #pragma unroll
        for (int o = 32; o > 0; o >>= 1) v += __shfl_xor(v, o);
        if (lane == 0) redbuf[r][wave] = v;
    }
    __syncthreads();
    #pragma unroll
    for (int r = 0; r < RQ; r++) {
        float v = 0.0f;
        #pragma unroll
        for (int w = 0; w < 8; w++) v += redbuf[r][w];
        const float rinv = frcp(v);
        out[(size_t)(b * TQ + q0 + r) * TK + t] = p[r] * rinv;
    }
}

extern "C" void kernel_launch(void* const* d_in, const int* in_sizes, int n_in,
                              void* d_out, int out_size, void* d_ws, size_t ws_size,
                              hipStream_t stream) {
    const float* query = (const float*)d_in[0];
    const float* value = (const float*)d_in[1];
    const float* W1    = (const float*)d_in[2];
    const float* W2    = (const float*)d_in[3];
    const float* scale = (const float*)d_in[4];
    float* out = (float*)d_out;

    float* Eq = (float*)d_ws;                     // [BB*TQ, UU]      2 MB
    float* Ek = Eq + (size_t)BB * TQ * UU;        // [BB,UU/4,TK] f4  2 MB
    (void)ws_size;  // needs 4 MB; harness provides >=13 MB (verified R7-R9)

    proj2<<<dim3(64, 4, 2), 256, 0, stream>>>(query, value, W1, W2, Eq, Ek);
    attn_softmax<<<dim3(BB * TQ / RQ), 512, 0, stream>>>(Eq, Ek, scale, out);
}

// Round 11
// 109.950 us; speedup vs baseline: 1.3011x; 1.3011x over previous
//
#include <hip/hip_runtime.h>

#define BB 4
#define TQ 512
#define TK 512
#define DQ 512
#define UU 256
#define CSC 2.8853900817779268f   // 2*log2(e): Eq=2^(CSC*q), Ek=2^(CSC*k), e^{2y}=Eq*Ek
#define L2E 1.4426950408889634f
#define RQ 2

typedef unsigned short u16;
typedef unsigned int u32;
typedef short bf16x8 __attribute__((ext_vector_type(8)));
typedef float f32x4 __attribute__((ext_vector_type(4)));

__device__ __forceinline__ float fexp2(float x) { return __builtin_amdgcn_exp2f(x); }
__device__ __forceinline__ float frcp(float x)  { return __builtin_amdgcn_rcpf(x); }
// pack high 16 bits of two fp32 words: low16 = a.hi16, high16 = b.hi16
__device__ __forceinline__ u32 pkhi(u32 a, u32 b) { return (b & 0xffff0000u) | (a >> 16); }

// proj2-dbuf: C = A@W, split-bf16 MFMA (truncation split, 3 terms), CSC+exp2 epilogue.
// Tile 32m x 64n, K chunks of 32, DOUBLE-BUFFERED LDS with 1 barrier/iter:
//   store(i)->buf[i&1]; issue loads(i+1); barrier; ds_read+MFMA(i)   -- loads for i+1
// are waited on only at store(i+1), a full iteration later (latency hidden).
// Grid (64,4,2) = 512 blocks (2/CU), block 256 = 4 waves; wave w owns n cols [16w,16w+16).
// z=0: Eq[m][u] row-major.  z=1: Ek interleaved [b][u/4][j][4] via LDS bounce.
__global__ __launch_bounds__(256) void proj2(
    const float* __restrict__ Aq, const float* __restrict__ Av,
    const float* __restrict__ W1, const float* __restrict__ W2,
    float* __restrict__ Eq, float* __restrict__ Ek)
{
    __shared__ __align__(16) char raw[28672];   // 2 x 14336: As_h 2560 | As_l 2560 | Ws 9216
    float* fin = (float*)raw;                   // [32][68] f32, aliases buf0 after last iter

    const int z = blockIdx.z;
    const float* A = z ? Av : Aq;
    const float* W = z ? W2 : W1;

    const int t = threadIdx.x;
    const int m0 = blockIdx.x * 32, n0 = blockIdx.y * 64;
    const int wave = t >> 6, ln = t & 15, qd = (t & 63) >> 4;
    const int arow = t >> 3, ak4 = (t & 7) * 4;    // A staging: 4 fp32/thread
    const int wk = t >> 4, wn4 = (t & 15) * 4;     // W staging: 2x4 fp32/thread

    f32x4 acc[2] = {};

    float4 a4  = *(const float4*)&A[(size_t)(m0 + arow) * DQ + ak4];
    float4 w40 = *(const float4*)&W[(size_t)wk * UU + n0 + wn4];
    float4 w41 = *(const float4*)&W[(size_t)(16 + wk) * UU + n0 + wn4];

    for (int i = 0; i < DQ / 32; i++) {
        char* buf = raw + (i & 1) * 14336;
        u16*   Ah_s = (u16*)buf;
        u16*   Al_s = (u16*)(buf + 2560);
        float* Ws_s = (float*)(buf + 5120);
        {   // A split -> bf16 hi/lo planes (done once by the loader thread)
            const float f[4] = {a4.x, a4.y, a4.z, a4.w};
            u32 x[4], lx[4];
            #pragma unroll
            for (int e = 0; e < 4; e++) {
                x[e]  = __float_as_uint(f[e]);
                lx[e] = __float_as_uint(f[e] - __uint_as_float(x[e] & 0xffff0000u));
            }
            uint2 hw, lw;
            hw.x = pkhi(x[0], x[1]);  hw.y = pkhi(x[2], x[3]);
            lw.x = pkhi(lx[0], lx[1]); lw.y = pkhi(lx[2], lx[3]);
            *(uint2*)&Ah_s[arow * 40 + ak4] = hw;
            *(uint2*)&Al_s[arow * 40 + ak4] = lw;
        }
        *(float4*)&Ws_s[wk * 72 + wn4] = w40;
        *(float4*)&Ws_s[(wk + 16) * 72 + wn4] = w41;

        if (i + 1 < DQ / 32) {       // prefetch next chunk; consumed at store(i+1)
            const int k0 = (i + 1) * 32;
            a4  = *(const float4*)&A[(size_t)(m0 + arow) * DQ + k0 + ak4];
            w40 = *(const float4*)&W[(size_t)(k0 + wk) * UU + n0 + wn4];
            w41 = *(const float4*)&W[(size_t)(k0 + 16 + wk) * UU + n0 + wn4];
        }
        __syncthreads();

        bf16x8 ah[2], al[2], bh, bl;
        #pragma unroll
        for (int ii = 0; ii < 2; ii++) {
            const int ar = (ii * 16 + ln) * 40 + qd * 8;
            ah[ii] = *(const bf16x8*)&Ah_s[ar];
            al[ii] = *(const bf16x8*)&Al_s[ar];
        }
        {   // W frag: col = wave*16+ln, 8 consecutive k; split in-reg (per-wave cols, no dup)
            const int cl = wave * 16 + ln;
            float wf[8];
            #pragma unroll
            for (int e = 0; e < 8; e++) wf[e] = Ws_s[(qd * 8 + e) * 72 + cl];
            u32 y[8], ly[8];
            #pragma unroll
            for (int e = 0; e < 8; e++) {
                y[e]  = __float_as_uint(wf[e]);
                ly[e] = __float_as_uint(wf[e] - __uint_as_float(y[e] & 0xffff0000u));
            }
            union { uint4 u; bf16x8 v; } h, l;
            h.u.x = pkhi(y[0], y[1]);  h.u.y = pkhi(y[2], y[3]);
            h.u.z = pkhi(y[4], y[5]);  h.u.w = pkhi(y[6], y[7]);
            l.u.x = pkhi(ly[0], ly[1]); l.u.y = pkhi(ly[2], ly[3]);
            l.u.z = pkhi(ly[4], ly[5]); l.u.w = pkhi(ly[6], ly[7]);
            bh = h.v; bl = l.v;
        }
        #pragma unroll
        for (int ii = 0; ii < 2; ii++) {
            acc[ii] = __builtin_amdgcn_mfma_f32_16x16x32_bf16(ah[ii], bh, acc[ii], 0, 0, 0);
            acc[ii] = __builtin_amdgcn_mfma_f32_16x16x32_bf16(ah[ii], bl, acc[ii], 0, 0, 0);
            acc[ii] = __builtin_amdgcn_mfma_f32_16x16x32_bf16(al[ii], bh, acc[ii], 0, 0, 0);
        }
    }

    const int ncol = n0 + wave * 16 + ln;
    if (z == 0) {
        #pragma unroll
        for (int ii = 0; ii < 2; ii++) {
            #pragma unroll
            for (int r = 0; r < 4; r++) {
                const int m = m0 + ii * 16 + qd * 4 + r;
                Eq[(size_t)m * UU + ncol] = fexp2(CSC * acc[ii][r]);
            }
        }
    } else {
        __syncthreads();   // all frag reads done before aliasing buf0 with fin
        #pragma unroll
        for (int ii = 0; ii < 2; ii++) {
            #pragma unroll
            for (int r = 0; r < 4; r++) {
                const int ml = ii * 16 + qd * 4 + r;          // j-local 0..31
                const int nl = wave * 16 + ln;                // u-local 0..63
                fin[ml * 68 + nl] = fexp2(CSC * acc[ii][r]);
            }
        }
        __syncthreads();
        const int b = m0 >> 9, j0 = m0 & 511;
        #pragma unroll
        for (int p = 0; p < 2; p++) {
            const int idx = p * 256 + t;
            const int jl = idx & 31, u4 = idx >> 5;           // u4 0..15
            const float4 v = *(const float4*)&fin[jl * 68 + u4 * 4];
            ((float4*)Ek)[(size_t)(b * (UU / 4) + (n0 >> 2) + u4) * TK + j0 + jl] = v;
        }
    }
}

// attn+softmax: e^{2y} = Eq*Ek; rcp paired over adjacent u (exact algebra):
// s0/d0 + s1/d1 = (s0*d1 + s1*d0)/(d0*d1); d in [1, 2^40] -> product <= 2^80? no:
// d0*d1 <= 2^52 typ (|x|<=20 sigma) -- fp32-safe. shifted_score = -2*sum (shift-inv).
// kbuf[2] with (g&1) under unroll-2 resolves to registers (R10's kbuf[4] got
// LDS-promoted: 33KB alloca + 1.9e7 bank conflicts -- do NOT deepen this buffer).
__global__ __launch_bounds__(512) void attn_softmax(
    const float* __restrict__ Eq,    // [BB, TQ, UU]
    const float* __restrict__ Ek,    // [BB, UU/4, TK] of float4 (interleaved u)
    const float* __restrict__ scale, // [UU]
    float* __restrict__ out)         // [BB, TQ, TK]
{
    __shared__ float redbuf[RQ][8];
    const int t  = threadIdx.x;
    const int b  = blockIdx.x >> 8;            // 256 blocks per b
    const int q0 = (blockIdx.x & 255) * RQ;
    const float*  qrow = Eq + (size_t)(b * TQ + q0) * UU;   // wave-uniform
    const float4* kb4  = (const float4*)Ek + (size_t)b * (UU / 4) * TK + t;

    float acc[RQ] = {};
    float4 kbuf[2];
    kbuf[0] = kb4[0];
    kbuf[1] = kb4[TK];

    #pragma unroll 2
    for (int g = 0; g < UU / 4; g++) {
        const float4 kv = kbuf[g & 1];
        if (g + 2 < UU / 4) kbuf[g & 1] = kb4[(size_t)(g + 2) * TK];  // 2-deep prefetch
        const float4 sc4 = *(const float4*)&scale[4 * g];             // wave-uniform
        const float* sf = (const float*)&sc4;
        const float* kf = (const float*)&kv;
        #pragma unroll
        for (int r = 0; r < RQ; r++) {
            const float4 q4 = *(const float4*)&qrow[(size_t)r * UU + 4 * g];
            const float* qf = (const float*)&q4;
            #pragma unroll
            for (int p = 0; p < 4; p += 2) {
                const float d0 = fmaf(qf[p],     kf[p],     1.0f);
                const float d1 = fmaf(qf[p + 1], kf[p + 1], 1.0f);
                const float num = fmaf(sf[p], d1, sf[p + 1] * d0);
                acc[r] = fmaf(num, frcp(d0 * d1), acc[r]);
            }
        }
    }
    #pragma unroll
    for (int r = 0; r < RQ; r++) acc[r] *= -2.0f;

    const int wave = t >> 6, lane = t & 63;
    float m[RQ], p[RQ];

    // row max over 512 threads
    #pragma unroll
    for (int r = 0; r < RQ; r++) {
        float v = acc[r];
        #pragma unroll
        for (int o = 32; o > 0; o >>= 1) v = fmaxf(v, __shfl_xor(v, o));
        if (lane == 0) redbuf[r][wave] = v;
    }
    __syncthreads();
    #pragma unroll
    for (int r = 0; r < RQ; r++) {
        float v = redbuf[r][0];
        #pragma unroll
        for (int w = 1; w < 8; w++) v = fmaxf(v, redbuf[r][w]);
        m[r] = v;
    }
    __syncthreads();

    // exp and row sum
    #pragma unroll
    for (int r = 0; r < RQ; r++) {
        p[r] = fexp2(L2E * (acc[r] - m[r]));
        float v = p[r];
        #pragma unroll
        for (int o = 32; o > 0; o >>= 1) v += __shfl_xor(v, o);
        if (lane == 0) redbuf[r][wave] = v;
    }
    __syncthreads();
    #pragma unroll
    for (int r = 0; r < RQ; r++) {
        float v = 0.0f;
        #pragma unroll
        for (int w = 0; w < 8; w++) v += redbuf[r][w];
        const float rinv = frcp(v);
        out[(size_t)(b * TQ + q0 + r) * TK + t] = p[r] * rinv;
    }
}

extern "C" void kernel_launch(void* const* d_in, const int* in_sizes, int n_in,
                              void* d_out, int out_size, void* d_ws, size_t ws_size,
                              hipStream_t stream) {
    const float* query = (const float*)d_in[0];
    const float* value = (const float*)d_in[1];
    const float* W1    = (const float*)d_in[2];
    const float* W2    = (const float*)d_in[3];
    const float* scale = (const float*)d_in[4];
    float* out = (float*)d_out;

    float* Eq = (float*)d_ws;                     // [BB*TQ, UU]      2 MB
    float* Ek = Eq + (size_t)BB * TQ * UU;        // [BB,UU/4,TK] f4  2 MB
    (void)ws_size;  // needs 4 MB; harness provides >=13 MB (verified R7-R10)

    proj2<<<dim3(64, 4, 2), 256, 0, stream>>>(query, value, W1, W2, Eq, Ek);
    attn_softmax<<<dim3(BB * TQ / RQ), 512, 0, stream>>>(Eq, Ek, scale, out);
}

// Round 12
// 107.945 us; speedup vs baseline: 1.3252x; 1.0186x over previous
//
#include <hip/hip_runtime.h>

#define BB 4
#define TQ 512
#define TK 512
#define DQ 512
#define UU 256
#define CSC 2.8853900817779268f   // 2*log2(e): Eq=2^(CSC*q), Ek=2^(CSC*k), e^{2y}=Eq*Ek
#define L2E 1.4426950408889634f
#define RQ 2

typedef unsigned short u16;
typedef unsigned int u32;
typedef short bf16x8 __attribute__((ext_vector_type(8)));
typedef float f32x4 __attribute__((ext_vector_type(4)));

__device__ __forceinline__ float fexp2(float x) { return __builtin_amdgcn_exp2f(x); }
__device__ __forceinline__ float frcp(float x)  { return __builtin_amdgcn_rcpf(x); }
__device__ __forceinline__ u32 pkhi(u32 a, u32 b) { return (b & 0xffff0000u) | (a >> 16); }

// wsplit: transpose+split W1/W2 (fp32 [512k][256n]) -> Wh_t/Wl_t (u16 [256n][512k]).
// 128 32x32 tiles per W; 256 blocks total. ~1.5 MB traffic -> ~2 us.
__global__ __launch_bounds__(256) void wsplit(
    const float* __restrict__ W1, const float* __restrict__ W2,
    u16* __restrict__ W1h, u16* __restrict__ W1l,
    u16* __restrict__ W2h, u16* __restrict__ W2l)
{
    __shared__ float tile[32][33];
    const int blk = blockIdx.x, t = threadIdx.x;
    const float* W = (blk >> 7) ? W2 : W1;
    u16* oh = (blk >> 7) ? W2h : W1h;
    u16* ol = (blk >> 7) ? W2l : W1l;
    const int tl = blk & 127;
    const int k0 = (tl >> 3) * 32, n0 = (tl & 7) * 32;
    const int kl = t >> 5, nl = t & 31;
    #pragma unroll
    for (int r = 0; r < 4; r++)
        tile[kl + 8 * r][nl] = W[(size_t)(k0 + kl + 8 * r) * UU + n0 + nl];
    __syncthreads();
    const int nr = t >> 5, kc = t & 31;
    #pragma unroll
    for (int r = 0; r < 4; r++) {
        const float v = tile[kc][nr + 8 * r];
        const u32 x = __float_as_uint(v);
        const u16 h = (u16)(x >> 16);
        const u16 l = (u16)(__float_as_uint(v - __uint_as_float(x & 0xffff0000u)) >> 16);
        oh[(size_t)(n0 + nr + 8 * r) * DQ + k0 + kc] = h;
        ol[(size_t)(n0 + nr + 8 * r) * DQ + k0 + kc] = l;
    }
}

// proj3: C = A@W, split-bf16 MFMA (truncation split, 3 terms), exp2(CSC*acc) epilogue.
// Tile 32m x 64n, K chunks of 32. A: global->split->LDS, double-buffered, 1 barrier/iter.
// W: pre-split planes, per-lane b128 global loads, register double-buffer issued AFTER
// the barrier so they drain at barrier(i+1) -- a full iteration of latency cover.
// Grid (64,4,2) = 512 blocks, block 256 = 4 waves; wave w owns n cols [16w,16w+16).
// z=0: Eq[m][u] row-major.  z=1: Ek interleaved [b][u/4][j][4] via LDS bounce.
__global__ __launch_bounds__(256) void proj3(
    const float* __restrict__ Aq, const float* __restrict__ Av,
    const u16* __restrict__ W1h, const u16* __restrict__ W1l,
    const u16* __restrict__ W2h, const u16* __restrict__ W2l,
    float* __restrict__ Eq, float* __restrict__ Ek)
{
    __shared__ __align__(16) char raw[10240];   // 2 x 5120: Ah [32][40] + Al [32][40] u16
    float* fin = (float*)raw;                   // [32][68] f32 (8704 B), aliases after barrier

    const int z = blockIdx.z;
    const float* A = z ? Av : Aq;
    const u16* Wh = z ? W2h : W1h;
    const u16* Wl = z ? W2l : W1l;

    const int t = threadIdx.x;
    const int m0 = blockIdx.x * 32, n0 = blockIdx.y * 64;
    const int wave = t >> 6, ln = t & 15, qd = (t & 63) >> 4;
    const int arow = t >> 3, ak4 = (t & 7) * 4;        // A staging: 4 fp32/thread
    const int ncol = n0 + wave * 16 + ln;
    const u16* whp = Wh + (size_t)ncol * DQ + qd * 8;  // + k0 per iter
    const u16* wlp = Wl + (size_t)ncol * DQ + qd * 8;

    f32x4 acc[2] = {};

    float4 a4 = *(const float4*)&A[(size_t)(m0 + arow) * DQ + ak4];
    bf16x8 whc = *(const bf16x8*)&whp[0];
    bf16x8 wlc = *(const bf16x8*)&wlp[0];

    for (int i = 0; i < DQ / 32; i++) {
        char* buf = raw + (i & 1) * 5120;
        u16* Ah_s = (u16*)buf;
        u16* Al_s = (u16*)(buf + 2560);
        {   // A split -> bf16 hi/lo planes
            const float f[4] = {a4.x, a4.y, a4.z, a4.w};
            u32 x[4], lx[4];
            #pragma unroll
            for (int e = 0; e < 4; e++) {
                x[e]  = __float_as_uint(f[e]);
                lx[e] = __float_as_uint(f[e] - __uint_as_float(x[e] & 0xffff0000u));
            }
            uint2 hw, lw;
            hw.x = pkhi(x[0], x[1]);  hw.y = pkhi(x[2], x[3]);
            lw.x = pkhi(lx[0], lx[1]); lw.y = pkhi(lx[2], lx[3]);
            *(uint2*)&Ah_s[arow * 40 + ak4] = hw;
            *(uint2*)&Al_s[arow * 40 + ak4] = lw;
        }
        if (i + 1 < DQ / 32)    // A prefetch; consumed at stage(i+1), pre-barrier
            a4 = *(const float4*)&A[(size_t)(m0 + arow) * DQ + (i + 1) * 32 + ak4];
        __syncthreads();

        bf16x8 whn, wln;
        if (i + 1 < DQ / 32) {  // W prefetch AFTER barrier -> drains at barrier(i+1)
            whn = *(const bf16x8*)&whp[(i + 1) * 32];
            wln = *(const bf16x8*)&wlp[(i + 1) * 32];
        }

        bf16x8 ah[2], al[2];
        #pragma unroll
        for (int ii = 0; ii < 2; ii++) {
            const int ar = (ii * 16 + ln) * 40 + qd * 8;
            ah[ii] = *(const bf16x8*)&Ah_s[ar];
            al[ii] = *(const bf16x8*)&Al_s[ar];
        }
        #pragma unroll
        for (int ii = 0; ii < 2; ii++) {
            acc[ii] = __builtin_amdgcn_mfma_f32_16x16x32_bf16(ah[ii], whc, acc[ii], 0, 0, 0);
            acc[ii] = __builtin_amdgcn_mfma_f32_16x16x32_bf16(ah[ii], wlc, acc[ii], 0, 0, 0);
            acc[ii] = __builtin_amdgcn_mfma_f32_16x16x32_bf16(al[ii], whc, acc[ii], 0, 0, 0);
        }
        whc = whn; wlc = wln;
    }

    if (z == 0) {
        #pragma unroll
        for (int ii = 0; ii < 2; ii++) {
            #pragma unroll
            for (int r = 0; r < 4; r++) {
                const int m = m0 + ii * 16 + qd * 4 + r;
                Eq[(size_t)m * UU + ncol] = fexp2(CSC * acc[ii][r]);
            }
        }
    } else {
        __syncthreads();   // all frag reads done before aliasing staging with fin
        #pragma unroll
        for (int ii = 0; ii < 2; ii++) {
            #pragma unroll
            for (int r = 0; r < 4; r++) {
                const int ml = ii * 16 + qd * 4 + r;          // j-local 0..31
                const int nl = wave * 16 + ln;                // u-local 0..63
                fin[ml * 68 + nl] = fexp2(CSC * acc[ii][r]);
            }
        }
        __syncthreads();
        const int b = m0 >> 9, j0 = m0 & 511;
        #pragma unroll
        for (int p = 0; p < 2; p++) {
            const int idx = p * 256 + t;
            const int jl = idx & 31, u4 = idx >> 5;           // u4 0..15
            const float4 v = *(const float4*)&fin[jl * 68 + u4 * 4];
            ((float4*)Ek)[(size_t)(b * (UU / 4) + (n0 >> 2) + u4) * TK + j0 + jl] = v;
        }
    }
}

// attn+softmax: e^{2y} = Eq*Ek; rcp paired over adjacent u (exact algebra):
// s0/d0 + s1/d1 = (s0*d1+s1*d0)/(d0*d1), d0*d1 fp32-safe. shifted_score = -2*sum.
// k prefetch: 4 NAMED float4 regs, statically indexed (R10's kbuf[4] with dynamic
// index got LDS-promoted: 33KB + 1.9e7 bank conflicts -- never use indexed arrays here).
__global__ __launch_bounds__(512) void attn_softmax(
    const float* __restrict__ Eq,    // [BB, TQ, UU]
    const float* __restrict__ Ek,    // [BB, UU/4, TK] of float4 (interleaved u)
    const float* __restrict__ scale, // [UU]
    float* __restrict__ out)         // [BB, TQ, TK]
{
    __shared__ float redbuf[RQ][8];
    const int t  = threadIdx.x;
    const int b  = blockIdx.x >> 8;            // 256 blocks per b
    const int q0 = (blockIdx.x & 255) * RQ;
    const float*  qrow = Eq + (size_t)(b * TQ + q0) * UU;   // wave-uniform
    const float4* kb4  = (const float4*)Ek + (size_t)b * (UU / 4) * TK + t;

    float acc[RQ] = {};

    auto body = [&](const float4& kv, int g) {
        const float4 sc4 = *(const float4*)&scale[4 * g];    // wave-uniform
        const float* sf = (const float*)&sc4;
        const float* kf = (const float*)&kv;
        #pragma unroll
        for (int r = 0; r < RQ; r++) {
            const float4 q4 = *(const float4*)&qrow[(size_t)r * UU + 4 * g];
            const float* qf = (const float*)&q4;
            #pragma unroll
            for (int p = 0; p < 4; p += 2) {
                const float d0 = fmaf(qf[p],     kf[p],     1.0f);
                const float d1 = fmaf(qf[p + 1], kf[p + 1], 1.0f);
                const float num = fmaf(sf[p], d1, sf[p + 1] * d0);
                acc[r] = fmaf(num, frcp(d0 * d1), acc[r]);
            }
        }
    };

    float4 c0 = kb4[0];
    float4 c1 = kb4[(size_t)TK];
    float4 c2 = kb4[(size_t)2 * TK];
    float4 c3 = kb4[(size_t)3 * TK];
    for (int g = 0; g < UU / 4; g += 4) {
        float4 n0v, n1v, n2v, n3v;
        if (g + 4 < UU / 4) {
            n0v = kb4[(size_t)(g + 4) * TK];
            n1v = kb4[(size_t)(g + 5) * TK];
            n2v = kb4[(size_t)(g + 6) * TK];
            n3v = kb4[(size_t)(g + 7) * TK];
        }
        body(c0, g); body(c1, g + 1); body(c2, g + 2); body(c3, g + 3);
        c0 = n0v; c1 = n1v; c2 = n2v; c3 = n3v;
    }
    #pragma unroll
    for (int r = 0; r < RQ; r++) acc[r] *= -2.0f;

    const int wave = t >> 6, lane = t & 63;
    float m[RQ], p[RQ];

    // row max over 512 threads
    #pragma unroll
    for (int r = 0; r < RQ; r++) {
        float v = acc[r];
        #pragma unroll
        for (int o = 32; o > 0; o >>= 1) v = fmaxf(v, __shfl_xor(v, o));
        if (lane == 0) redbuf[r][wave] = v;
    }
    __syncthreads();
    #pragma unroll
    for (int r = 0; r < RQ; r++) {
        float v = redbuf[r][0];
        #pragma unroll
        for (int w = 1; w < 8; w++) v = fmaxf(v, redbuf[r][w]);
        m[r] = v;
    }
    __syncthreads();

    // exp and row sum
    #pragma unroll
    for (int r = 0; r < RQ; r++) {
        p[r] = fexp2(L2E * (acc[r] - m[r]));
        float v = p[r];
        #pragma unroll
        for (int o = 32; o > 0; o >>= 1) v += __shfl_xor(v, o);
        if (lane == 0) redbuf[r][wave] = v;
    }
    __syncthreads();
    #pragma unroll
    for (int r = 0; r < RQ; r++) {
        float v = 0.0f;
        #pragma unroll
        for (int w = 0; w < 8; w++) v += redbuf[r][w];
        const float rinv = frcp(v);
        out[(size_t)(b * TQ + q0 + r) * TK + t] = p[r] * rinv;
    }
}

extern "C" void kernel_launch(void* const* d_in, const int* in_sizes, int n_in,
                              void* d_out, int out_size, void* d_ws, size_t ws_size,
                              hipStream_t stream) {
    const float* query = (const float*)d_in[0];
    const float* value = (const float*)d_in[1];
    const float* W1    = (const float*)d_in[2];
    const float* W2    = (const float*)d_in[3];
    const float* scale = (const float*)d_in[4];
    float* out = (float*)d_out;

    float* Eq = (float*)d_ws;                     // [BB*TQ, UU]      2 MB
    float* Ek = Eq + (size_t)BB * TQ * UU;        // [BB,UU/4,TK] f4  2 MB
    char* wbase = (char*)d_ws + 4 * 1048576;      // W planes: 4 x 256 KB
    u16* W1h = (u16*)(wbase);
    u16* W1l = (u16*)(wbase + 262144);
    u16* W2h = (u16*)(wbase + 524288);
    u16* W2l = (u16*)(wbase + 786432);
    (void)ws_size;  // needs 5 MB; harness provides 256 MB (verified R11 profile)

    wsplit<<<256, 256, 0, stream>>>(W1, W2, W1h, W1l, W2h, W2l);
    proj3<<<dim3(64, 4, 2), 256, 0, stream>>>(query, value, W1h, W1l, W2h, W2l, Eq, Ek);
    attn_softmax<<<dim3(BB * TQ / RQ), 512, 0, stream>>>(Eq, Ek, scale, out);
}

// Round 13
// 106.195 us; speedup vs baseline: 1.3471x; 1.0165x over previous
//
#include <hip/hip_runtime.h>

#define BB 4
#define TQ 512
#define TK 512
#define DQ 512
#define UU 256
#define CSC 2.8853900817779268f   // 2*log2(e): Eq=2^(CSC*q), Ek=2^(CSC*k), e^{2y}=Eq*Ek
#define L2E 1.4426950408889634f
#define RQ 4

typedef unsigned short u16;
typedef unsigned int u32;
typedef short bf16x8 __attribute__((ext_vector_type(8)));
typedef float f32x4 __attribute__((ext_vector_type(4)));

__device__ __forceinline__ float fexp2(float x) { return __builtin_amdgcn_exp2f(x); }
__device__ __forceinline__ float frcp(float x)  { return __builtin_amdgcn_rcpf(x); }
__device__ __forceinline__ u32 pkhi(u32 a, u32 b) { return (b & 0xffff0000u) | (a >> 16); }

// wsplit: transpose+split W1/W2 (fp32 [512k][256n]) -> Wh_t/Wl_t (u16 [256n][512k]).
__global__ __launch_bounds__(256) void wsplit(
    const float* __restrict__ W1, const float* __restrict__ W2,
    u16* __restrict__ W1h, u16* __restrict__ W1l,
    u16* __restrict__ W2h, u16* __restrict__ W2l)
{
    __shared__ float tile[32][33];
    const int blk = blockIdx.x, t = threadIdx.x;
    const float* W = (blk >> 7) ? W2 : W1;
    u16* oh = (blk >> 7) ? W2h : W1h;
    u16* ol = (blk >> 7) ? W2l : W1l;
    const int tl = blk & 127;
    const int k0 = (tl >> 3) * 32, n0 = (tl & 7) * 32;
    const int kl = t >> 5, nl = t & 31;
    #pragma unroll
    for (int r = 0; r < 4; r++)
        tile[kl + 8 * r][nl] = W[(size_t)(k0 + kl + 8 * r) * UU + n0 + nl];
    __syncthreads();
    const int nr = t >> 5, kc = t & 31;
    #pragma unroll
    for (int r = 0; r < 4; r++) {
        const float v = tile[kc][nr + 8 * r];
        const u32 x = __float_as_uint(v);
        const u16 h = (u16)(x >> 16);
        const u16 l = (u16)(__float_as_uint(v - __uint_as_float(x & 0xffff0000u)) >> 16);
        oh[(size_t)(n0 + nr + 8 * r) * DQ + k0 + kc] = h;
        ol[(size_t)(n0 + nr + 8 * r) * DQ + k0 + kc] = l;
    }
}

// proj3: C = A@W, split-bf16 MFMA (truncation split, 3 terms), exp2(CSC*acc) epilogue.
// Tile 32m x 64n, K chunks of 32. A: global->split->LDS, double-buffered, 1 barrier/iter.
// W: pre-split planes, per-lane b128 global loads, register double-buffer issued AFTER
// the barrier so they drain at barrier(i+1). Grid (64,4,2) = 512 blocks, 4 waves each.
// z=0: Eq[m][u] row-major.  z=1: Ek interleaved [b][u/4][j][4] via LDS bounce.
__global__ __launch_bounds__(256) void proj3(
    const float* __restrict__ Aq, const float* __restrict__ Av,
    const u16* __restrict__ W1h, const u16* __restrict__ W1l,
    const u16* __restrict__ W2h, const u16* __restrict__ W2l,
    float* __restrict__ Eq, float* __restrict__ Ek)
{
    __shared__ __align__(16) char raw[10240];   // 2 x 5120: Ah [32][40] + Al [32][40] u16
    float* fin = (float*)raw;                   // [32][68] f32, aliases after final barrier

    const int z = blockIdx.z;
    const float* A = z ? Av : Aq;
    const u16* Wh = z ? W2h : W1h;
    const u16* Wl = z ? W2l : W1l;

    const int t = threadIdx.x;
    const int m0 = blockIdx.x * 32, n0 = blockIdx.y * 64;
    const int wave = t >> 6, ln = t & 15, qd = (t & 63) >> 4;
    const int arow = t >> 3, ak4 = (t & 7) * 4;        // A staging: 4 fp32/thread
    const int ncol = n0 + wave * 16 + ln;
    const u16* whp = Wh + (size_t)ncol * DQ + qd * 8;
    const u16* wlp = Wl + (size_t)ncol * DQ + qd * 8;

    f32x4 acc[2] = {};

    float4 a4 = *(const float4*)&A[(size_t)(m0 + arow) * DQ + ak4];
    bf16x8 whc = *(const bf16x8*)&whp[0];
    bf16x8 wlc = *(const bf16x8*)&wlp[0];

    for (int i = 0; i < DQ / 32; i++) {
        char* buf = raw + (i & 1) * 5120;
        u16* Ah_s = (u16*)buf;
        u16* Al_s = (u16*)(buf + 2560);
        {   // A split -> bf16 hi/lo planes
            const float f[4] = {a4.x, a4.y, a4.z, a4.w};
            u32 x[4], lx[4];
            #pragma unroll
            for (int e = 0; e < 4; e++) {
                x[e]  = __float_as_uint(f[e]);
                lx[e] = __float_as_uint(f[e] - __uint_as_float(x[e] & 0xffff0000u));
            }
            uint2 hw, lw;
            hw.x = pkhi(x[0], x[1]);  hw.y = pkhi(x[2], x[3]);
            lw.x = pkhi(lx[0], lx[1]); lw.y = pkhi(lx[2], lx[3]);
            *(uint2*)&Ah_s[arow * 40 + ak4] = hw;
            *(uint2*)&Al_s[arow * 40 + ak4] = lw;
        }
        if (i + 1 < DQ / 32)
            a4 = *(const float4*)&A[(size_t)(m0 + arow) * DQ + (i + 1) * 32 + ak4];
        __syncthreads();

        bf16x8 whn, wln;
        if (i + 1 < DQ / 32) {  // W prefetch AFTER barrier -> drains at barrier(i+1)
            whn = *(const bf16x8*)&whp[(i + 1) * 32];
            wln = *(const bf16x8*)&wlp[(i + 1) * 32];
        }

        bf16x8 ah[2], al[2];
        #pragma unroll
        for (int ii = 0; ii < 2; ii++) {
            const int ar = (ii * 16 + ln) * 40 + qd * 8;
            ah[ii] = *(const bf16x8*)&Ah_s[ar];
            al[ii] = *(const bf16x8*)&Al_s[ar];
        }
        #pragma unroll
        for (int ii = 0; ii < 2; ii++) {
            acc[ii] = __builtin_amdgcn_mfma_f32_16x16x32_bf16(ah[ii], whc, acc[ii], 0, 0, 0);
            acc[ii] = __builtin_amdgcn_mfma_f32_16x16x32_bf16(ah[ii], wlc, acc[ii], 0, 0, 0);
            acc[ii] = __builtin_amdgcn_mfma_f32_16x16x32_bf16(al[ii], whc, acc[ii], 0, 0, 0);
        }
        whc = whn; wlc = wln;
    }

    if (z == 0) {
        #pragma unroll
        for (int ii = 0; ii < 2; ii++) {
            #pragma unroll
            for (int r = 0; r < 4; r++) {
                const int m = m0 + ii * 16 + qd * 4 + r;
                Eq[(size_t)m * UU + ncol] = fexp2(CSC * acc[ii][r]);
            }
        }
    } else {
        __syncthreads();
        #pragma unroll
        for (int ii = 0; ii < 2; ii++) {
            #pragma unroll
            for (int r = 0; r < 4; r++) {
                const int ml = ii * 16 + qd * 4 + r;
                const int nl = wave * 16 + ln;
                fin[ml * 68 + nl] = fexp2(CSC * acc[ii][r]);
            }
        }
        __syncthreads();
        const int b = m0 >> 9, j0 = m0 & 511;
        #pragma unroll
        for (int p = 0; p < 2; p++) {
            const int idx = p * 256 + t;
            const int jl = idx & 31, u4 = idx >> 5;
            const float4 v = *(const float4*)&fin[jl * 68 + u4 * 4];
            ((float4*)Ek)[(size_t)(b * (UU / 4) + (n0 >> 2) + u4) * TK + j0 + jl] = v;
        }
    }
}

// attn+softmax: e^{2y} = Eq*Ek; rcp paired over adjacent u (exact algebra):
// s0/d0 + s1/d1 = (s0*d1+s1*d0)/(d0*d1). shifted_score = -2*sum (shift-invariant).
// RQ=4 q-rows/block: each float4 k-load feeds 16 elements (halves Ek L2 traffic vs RQ=2).
// k prefetch: NAMED float4 regs, statically indexed (R10's dynamically-indexed kbuf[4]
// got LDS-promoted: 33KB alloca + 1.9e7 bank conflicts -- never index these).
__global__ __launch_bounds__(512) void attn_softmax(
    const float* __restrict__ Eq,    // [BB, TQ, UU]
    const float* __restrict__ Ek,    // [BB, UU/4, TK] of float4 (interleaved u)
    const float* __restrict__ scale, // [UU]
    float* __restrict__ out)         // [BB, TQ, TK]
{
    __shared__ float redbuf[RQ][8];
    const int t  = threadIdx.x;
    const int b  = blockIdx.x >> 7;            // 128 blocks per b
    const int q0 = (blockIdx.x & 127) * RQ;
    const float*  qrow = Eq + (size_t)(b * TQ + q0) * UU;   // wave-uniform
    const float4* kb4  = (const float4*)Ek + (size_t)b * (UU / 4) * TK + t;

    float acc[RQ] = {};

    auto body = [&](const float4& kv, int g) {
        const float4 sc4 = *(const float4*)&scale[4 * g];    // wave-uniform
        const float* sf = (const float*)&sc4;
        const float* kf = (const float*)&kv;
        #pragma unroll
        for (int r = 0; r < RQ; r++) {
            const float4 q4 = *(const float4*)&qrow[(size_t)r * UU + 4 * g];
            const float* qf = (const float*)&q4;
            #pragma unroll
            for (int p = 0; p < 4; p += 2) {
                const float d0 = fmaf(qf[p],     kf[p],     1.0f);
                const float d1 = fmaf(qf[p + 1], kf[p + 1], 1.0f);
                const float num = fmaf(sf[p], d1, sf[p + 1] * d0);
                acc[r] = fmaf(num, frcp(d0 * d1), acc[r]);
            }
        }
    };

    float4 c0 = kb4[0];
    float4 c1 = kb4[(size_t)TK];
    float4 c2 = kb4[(size_t)2 * TK];
    float4 c3 = kb4[(size_t)3 * TK];
    for (int g = 0; g < UU / 4; g += 4) {
        float4 n0v, n1v, n2v, n3v;
        if (g + 4 < UU / 4) {
            n0v = kb4[(size_t)(g + 4) * TK];
            n1v = kb4[(size_t)(g + 5) * TK];
            n2v = kb4[(size_t)(g + 6) * TK];
            n3v = kb4[(size_t)(g + 7) * TK];
        }
        body(c0, g); body(c1, g + 1); body(c2, g + 2); body(c3, g + 3);
        c0 = n0v; c1 = n1v; c2 = n2v; c3 = n3v;
    }
    #pragma unroll
    for (int r = 0; r < RQ; r++) acc[r] *= -2.0f;

    const int wave = t >> 6, lane = t & 63;
    float m[RQ], p[RQ];

    // row max over 512 threads
    #pragma unroll
    for (int r = 0; r < RQ; r++) {
        float v = acc[r];
        #pragma unroll
        for (int o = 32; o > 0; o >>= 1) v = fmaxf(v, __shfl_xor(v, o));
        if (lane == 0) redbuf[r][wave] = v;
    }
    __syncthreads();
    #pragma unroll
    for (int r = 0; r < RQ; r++) {
        float v = redbuf[r][0];
        #pragma unroll
        for (int w = 1; w < 8; w++) v = fmaxf(v, redbuf[r][w]);
        m[r] = v;
    }
    __syncthreads();

    // exp and row sum
    #pragma unroll
    for (int r = 0; r < RQ; r++) {
        p[r] = fexp2(L2E * (acc[r] - m[r]));
        float v = p[r];
        #pragma unroll
        for (int o = 32; o > 0; o >>= 1) v += __shfl_xor(v, o);
        if (lane == 0) redbuf[r][wave] = v;
    }
    __syncthreads();
    #pragma unroll
    for (int r = 0; r < RQ; r++) {
        float v = 0.0f;
        #pragma unroll
        for (int w = 0; w < 8; w++) v += redbuf[r][w];
        const float rinv = frcp(v);
        out[(size_t)(b * TQ + q0 + r) * TK + t] = p[r] * rinv;
    }
}

extern "C" void kernel_launch(void* const* d_in, const int* in_sizes, int n_in,
                              void* d_out, int out_size, void* d_ws, size_t ws_size,
                              hipStream_t stream) {
    const float* query = (const float*)d_in[0];
    const float* value = (const float*)d_in[1];
    const float* W1    = (const float*)d_in[2];
    const float* W2    = (const float*)d_in[3];
    const float* scale = (const float*)d_in[4];
    float* out = (float*)d_out;

    float* Eq = (float*)d_ws;                     // [BB*TQ, UU]      2 MB
    float* Ek = Eq + (size_t)BB * TQ * UU;        // [BB,UU/4,TK] f4  2 MB
    char* wbase = (char*)d_ws + 4 * 1048576;      // W planes: 4 x 256 KB
    u16* W1h = (u16*)(wbase);
    u16* W1l = (u16*)(wbase + 262144);
    u16* W2h = (u16*)(wbase + 524288);
    u16* W2l = (u16*)(wbase + 786432);
    (void)ws_size;  // needs 5 MB; harness provides 256 MB (verified R11/R12 profile)

    wsplit<<<256, 256, 0, stream>>>(W1, W2, W1h, W1l, W2h, W2l);
    proj3<<<dim3(64, 4, 2), 256, 0, stream>>>(query, value, W1h, W1l, W2h, W2l, Eq, Ek);
    attn_softmax<<<dim3(BB * TQ / RQ), 512, 0, stream>>>(Eq, Ek, scale, out);
}